// Round 3
// baseline (3194.868 us; speedup 1.0000x reference)
//
#include <hip/hip_runtime.h>

// Problem constants (fixed by reference)
constexpr int BATCH = 256;
constexpr int TSTEPS = 250;
constexpr int NI = 700;
constexpr int NH = 512;
constexpr int NO = 20;
constexpr int NT = 1024;      // threads per block
constexpr int NWAVE = 16;

#define B_J0  0.01f
#define BETA_ 1.8f

// ---------------------------------------------------------------------------
// Tiled transpose with optional mask fused:  out[c*R + r] = in[r*C + c] * mask[c*R + r]
__global__ void transpose_mask(const float* __restrict__ in, const float* __restrict__ mask,
                               float* __restrict__ out, int R, int C) {
    __shared__ float tile[32][33];
    int cb = blockIdx.x * 32, rb = blockIdx.y * 32;
    int tx = threadIdx.x, ty = threadIdx.y;   // block (32,8)
    #pragma unroll
    for (int i = 0; i < 32; i += 8) {
        int r = rb + ty + i, c = cb + tx;
        if (r < R && c < C) tile[ty + i][tx] = in[(size_t)r * C + c];
    }
    __syncthreads();
    #pragma unroll
    for (int i = 0; i < 32; i += 8) {
        int c = cb + ty + i, r = rb + tx;
        if (c < C && r < R) {
            float v = tile[tx][ty + i];
            if (mask) v *= mask[(size_t)c * R + r];
            out[(size_t)c * R + r] = v;
        }
    }
}

__global__ void transpose_wout(const float* __restrict__ in, float* __restrict__ out) {
    int idx = blockIdx.x * blockDim.x + threadIdx.x;
    if (idx < NH * NO) {
        int j = idx / NO, o = idx % NO;
        out[idx] = in[o * NH + j];
    }
}

// A_norm: deterministic two-stage reduction
__global__ void anorm_stage1(const float* __restrict__ Wh11, const float* __restrict__ Wh22,
                             const float* __restrict__ mask, float* __restrict__ partial) {
    __shared__ float red[256];
    int tid = threadIdx.x;
    float s = 0.f;
    for (int idx = blockIdx.x * 256 + tid; idx < NH * NH; idx += 256 * 128) {
        int hh = idx / NH, j = idx % NH;
        s += fabsf(Wh11[idx] * mask[j * NH + hh]);
        s += fabsf(Wh22[idx] * mask[NH * NH + j * NH + hh]);
    }
    red[tid] = s;
    __syncthreads();
    for (int st = 128; st > 0; st >>= 1) {
        if (tid < st) red[tid] += red[tid + st];
        __syncthreads();
    }
    if (tid == 0) partial[blockIdx.x] = red[0];
}

__global__ void anorm_stage2(const float* __restrict__ partial, float* __restrict__ out) {
    __shared__ float red[128];
    int tid = threadIdx.x;
    red[tid] = partial[tid];
    __syncthreads();
    for (int st = 64; st > 0; st >>= 1) {
        if (tid < st) red[tid] += red[tid + st];
        __syncthreads();
    }
    if (tid == 0) out[0] = red[0];
}

// Deterministic, order-preserving block-wide stream compaction (16 waves).
__device__ __forceinline__ int block_compact(bool flag, int idx, int* list, int base,
                                             int* waveCnt, int tid) {
    unsigned long long m = __ballot(flag ? 1 : 0);
    int lane = tid & 63, w = tid >> 6;
    if (lane == 0) waveCnt[w] = __popcll(m);
    __syncthreads();
    int c[NWAVE];
    #pragma unroll
    for (int i = 0; i < NWAVE; ++i) c[i] = waveCnt[i];
    int off = base, tot = base;
    #pragma unroll
    for (int i = 0; i < NWAVE; ++i) {
        if (i < w) off += c[i];
        tot += c[i];
    }
    if (flag) list[off + __popcll(m & ((1ull << lane) - 1ull))] = idx;
    __syncthreads();
    return tot;
}

__device__ __forceinline__ void f4add(float4& a, const float4 b) {
    a.x += b.x; a.y += b.y; a.z += b.z; a.w += b.w;
}

__device__ __forceinline__ float4 ld4(const float* __restrict__ W, int j, int q) {
    return *reinterpret_cast<const float4*>(W + ((size_t)j << 9) + (q << 2));
}

// Gather a slice [kb,ke) of active rows of W with 8 float4 accumulators (MLP=8).
__device__ __forceinline__ float4 gather_slice(const int* __restrict__ list, int kb, int ke,
                                               const float* __restrict__ W, int q) {
    float4 a0{0,0,0,0}, a1{0,0,0,0}, a2{0,0,0,0}, a3{0,0,0,0},
           a4{0,0,0,0}, a5{0,0,0,0}, a6{0,0,0,0}, a7{0,0,0,0};
    int k = kb;
    for (; k + 7 < ke; k += 8) {
        int j0 = list[k],     j1 = list[k + 1], j2 = list[k + 2], j3 = list[k + 3];
        int j4 = list[k + 4], j5 = list[k + 5], j6 = list[k + 6], j7 = list[k + 7];
        f4add(a0, ld4(W, j0, q)); f4add(a1, ld4(W, j1, q));
        f4add(a2, ld4(W, j2, q)); f4add(a3, ld4(W, j3, q));
        f4add(a4, ld4(W, j4, q)); f4add(a5, ld4(W, j5, q));
        f4add(a6, ld4(W, j6, q)); f4add(a7, ld4(W, j7, q));
    }
    for (; k < ke; ++k) f4add(a0, ld4(W, list[k], q));
    f4add(a0, a1); f4add(a2, a3); f4add(a4, a5); f4add(a6, a7);
    f4add(a0, a2); f4add(a4, a6); f4add(a0, a4);
    return a0;
}

// ---------------------------------------------------------------------------
// Main kernel: one block per batch sample, 1024 threads (16 waves), full T loop.
__global__ __launch_bounds__(NT) void snn_kernel(
    const float* __restrict__ input,
    const float* __restrict__ h1m0, const float* __restrict__ h2m0, const float* __restrict__ om0,
    const float* __restrict__ b_in, const float* __restrict__ b_h11,
    const float* __restrict__ b_h12, const float* __restrict__ b_h22,
    const float* __restrict__ b_o,
    const float* __restrict__ tau_adp_h1, const float* __restrict__ tau_adp_h2,
    const float* __restrict__ tau_m_h1, const float* __restrict__ tau_m_h2,
    const float* __restrict__ tau_m_o,
    const float* __restrict__ WinT, const float* __restrict__ Wh11T,
    const float* __restrict__ Wh12T, const float* __restrict__ Wh22T,
    const float* __restrict__ WoutT,
    float* __restrict__ out)
{
    __shared__ int actIn[NI];
    __shared__ int actS1[NH];
    __shared__ int actS2[NH];
    __shared__ int waveCnt[NWAVE];
    __shared__ float4 part4[8 * 128];     // 8 slices x 128 float4 = 16 KB
    __shared__ float part[320];

    const int tid = threadIdx.x;
    const int b = blockIdx.x;
    const int h = tid;            // neuron id (valid when tid < NH)
    const int s = tid >> 7;       // k-slice 0..7
    const int q = tid & 127;      // float4 column group
    const bool isN = tid < NH;
    const bool isI = tid < NI;

    float mem1 = 0.f, mem2 = 0.f, spk1 = 0.f, spk2 = 0.f, s1c = 0.f, s2c = 0.f;
    float al1 = 0.f, al2 = 0.f, ro1 = 0.f, ro2 = 0.f, bs1 = 0.f, bs2 = 0.f;
    if (isN) {
        mem1 = h1m0[b * NH + h];
        mem2 = h2m0[b * NH + h];
        al1 = expf(-1.f / tau_m_h1[h]);
        al2 = expf(-1.f / tau_m_h2[h]);
        ro1 = expf(-1.f / tau_adp_h1[h]);
        ro2 = expf(-1.f / tau_adp_h2[h]);
        bs1 = b_in[h] + b_h11[h];
        bs2 = b_h12[h] + b_h22[h];
    }

    float outm = 0.f, accO = 0.f, alo = 0.f, bo = 0.f;
    if (tid < NO) {
        outm = om0[b * NO + tid];
        alo = expf(-1.f / tau_m_o[tid]);
        bo = b_o[tid];
    }

    int nS1 = 0, nS2 = 0;
    const float* xbase = input + (size_t)b * TSTEPS * NI;

    // preload step-0 input (non-temporal: streamed once, keep weights in L2)
    float x0 = isI ? __builtin_nontemporal_load(xbase + tid) : 0.f;

    for (int t = 0; t < TSTEPS; ++t) {
        // ---- active input list (single compact over 700 indices, order preserved)
        bool f0 = x0 > 0.f;
        int nIn = block_compact(f0, tid, actIn, 0, waveCnt, tid);

        // prefetch next step's input; latency hides under the gather below
        if (t + 1 < TSTEPS && isI)
            x0 = __builtin_nontemporal_load(xbase + (size_t)(t + 1) * NI + tid);

        // ---- layer 1 gather: slice s of {active inputs -> WinT} + {active spk1 -> Wh11T}
        {
            float4 p = gather_slice(actIn, (nIn * s) >> 3, (nIn * (s + 1)) >> 3, WinT, q);
            float4 p2 = gather_slice(actS1, (nS1 * s) >> 3, (nS1 * (s + 1)) >> 3, Wh11T, q);
            f4add(p, p2);
            part4[(s << 7) + q] = p;
        }
        __syncthreads();
        const float* pf = (const float*)part4;
        float ns1 = 0.f;
        if (isN) {
            float i1 = (((pf[h] + pf[NH + h]) + (pf[2 * NH + h] + pf[3 * NH + h])) +
                        ((pf[4 * NH + h] + pf[5 * NH + h]) + (pf[6 * NH + h] + pf[7 * NH + h]))) + bs1;
            float b1 = ro1 * B_J0 + (1.f - ro1) * spk1;
            float B1 = B_J0 + BETA_ * b1;
            mem1 = mem1 * al1 + (1.f - al1) * i1 - B1 * spk1;
            ns1 = (mem1 - B1) > 0.f ? 1.f : 0.f;
            spk1 = ns1;
            s1c += ns1;
        }
        nS1 = block_compact(ns1 != 0.f, tid, actS1, 0, waveCnt, tid);

        // ---- layer 2 gather: {new spk1 -> Wh12T} + {old spk2 -> Wh22T}
        {
            float4 p = gather_slice(actS1, (nS1 * s) >> 3, (nS1 * (s + 1)) >> 3, Wh12T, q);
            float4 p2 = gather_slice(actS2, (nS2 * s) >> 3, (nS2 * (s + 1)) >> 3, Wh22T, q);
            f4add(p, p2);
            part4[(s << 7) + q] = p;
        }
        __syncthreads();
        float ns2 = 0.f;
        if (isN) {
            float i2 = (((pf[h] + pf[NH + h]) + (pf[2 * NH + h] + pf[3 * NH + h])) +
                        ((pf[4 * NH + h] + pf[5 * NH + h]) + (pf[6 * NH + h] + pf[7 * NH + h]))) + bs2;
            float b2 = ro2 * B_J0 + (1.f - ro2) * spk2;
            float B2 = B_J0 + BETA_ * b2;
            mem2 = mem2 * al2 + (1.f - al2) * i2 - B2 * spk2;
            ns2 = (mem2 - B2) > 0.f ? 1.f : 0.f;
            spk2 = ns2;
            s2c += ns2;
        }
        nS2 = block_compact(ns2 != 0.f, tid, actS2, 0, waveCnt, tid);

        // ---- readout: partials by 320 threads, finish inside wave 0 (no extra barriers)
        if (tid < 320) {
            int o = tid % NO, r = tid / NO;
            float p = 0.f;
            for (int kk = r; kk < nS2; kk += 16) p += WoutT[actS2[kk] * NO + o];
            part[tid] = p;
        }
        __syncthreads();
        if (tid < 64) {
            float io = bo, v = -__builtin_huge_valf(), e = 0.f;
            if (tid < NO) {
                #pragma unroll
                for (int r = 0; r < 16; ++r) io += part[r * NO + tid];
                outm = outm * alo + (1.f - alo) * io;
                v = outm;
            }
            float mx = v;
            #pragma unroll
            for (int off = 16; off > 0; off >>= 1) mx = fmaxf(mx, __shfl_xor(mx, off, 32));
            if (tid < NO) e = expf(outm - mx);
            float ssum = e;
            #pragma unroll
            for (int off = 16; off > 0; off >>= 1) ssum += __shfl_xor(ssum, off, 32);
            if (tid < NO) accO += e / ssum;
        }
        // next loop's compact barrier orders part[] reuse
    }

    // ---- epilogue
    if (tid < NO) out[b * NO + tid] = accO;
    if (isN) {
        out[BATCH * NO + (size_t)b * NH + h] = s1c * (1.f / TSTEPS);
        out[BATCH * NO + BATCH * NH + (size_t)b * NH + h] = s2c * (1.f / TSTEPS);
    }
}

// ---------------------------------------------------------------------------
extern "C" void kernel_launch(void* const* d_in, const int* in_sizes, int n_in,
                              void* d_out, int out_size, void* d_ws, size_t ws_size,
                              hipStream_t stream) {
    const float* input      = (const float*)d_in[0];
    const float* mask       = (const float*)d_in[1];
    const float* h1m0       = (const float*)d_in[2];
    const float* h2m0       = (const float*)d_in[3];
    const float* om0        = (const float*)d_in[4];
    const float* W_in       = (const float*)d_in[5];
    const float* b_in       = (const float*)d_in[6];
    const float* W_h11      = (const float*)d_in[7];
    const float* b_h11      = (const float*)d_in[8];
    const float* W_h12      = (const float*)d_in[9];
    const float* b_h12      = (const float*)d_in[10];
    const float* W_h22      = (const float*)d_in[11];
    const float* b_h22      = (const float*)d_in[12];
    const float* W_out      = (const float*)d_in[13];
    const float* b_o        = (const float*)d_in[14];
    const float* tau_adp_h1 = (const float*)d_in[15];
    const float* tau_adp_h2 = (const float*)d_in[16];
    const float* tau_m_h1   = (const float*)d_in[17];
    const float* tau_m_h2   = (const float*)d_in[18];
    const float* tau_m_o    = (const float*)d_in[19];

    float* out = (float*)d_out;
    float* ws  = (float*)d_ws;

    float* WinT  = ws;                   // 700*512
    float* Wh11T = WinT + NI * NH;       // 512*512
    float* Wh12T = Wh11T + NH * NH;
    float* Wh22T = Wh12T + NH * NH;
    float* WoutT = Wh22T + NH * NH;      // 512*20
    float* apart = WoutT + NH * NO;      // 128 partials for anorm

    dim3 tb(32, 8);
    transpose_mask<<<dim3((NI + 31) / 32, (NH + 31) / 32), tb, 0, stream>>>(W_in, nullptr, WinT, NH, NI);
    transpose_mask<<<dim3(16, 16), tb, 0, stream>>>(W_h11, mask,            Wh11T, NH, NH);
    transpose_mask<<<dim3(16, 16), tb, 0, stream>>>(W_h12, nullptr,         Wh12T, NH, NH);
    transpose_mask<<<dim3(16, 16), tb, 0, stream>>>(W_h22, mask + NH * NH,  Wh22T, NH, NH);
    transpose_wout<<<(NH * NO + 255) / 256, 256, 0, stream>>>(W_out, WoutT);
    anorm_stage1<<<128, 256, 0, stream>>>(W_h11, W_h22, mask, apart);
    anorm_stage2<<<1, 128, 0, stream>>>(apart, out + BATCH * NO + 2 * BATCH * NH);

    snn_kernel<<<BATCH, NT, 0, stream>>>(input, h1m0, h2m0, om0,
        b_in, b_h11, b_h12, b_h22, b_o,
        tau_adp_h1, tau_adp_h2, tau_m_h1, tau_m_h2, tau_m_o,
        WinT, Wh11T, Wh12T, Wh22T, WoutT, out);
}

// Round 4
// 2876.709 us; speedup vs baseline: 1.1106x; 1.1106x over previous
//
#include <hip/hip_runtime.h>

// Problem constants (fixed by reference)
constexpr int BATCH = 256;
constexpr int TSTEPS = 250;
constexpr int NI = 700;
constexpr int NH = 512;
constexpr int NO = 20;
constexpr int NT = 1024;      // threads per block
constexpr int NWAVE = 16;

#define B_J0  0.01f
#define BETA_ 1.8f

// ---------------------------------------------------------------------------
// Tiled transpose with optional mask fused:  out[c*R + r] = in[r*C + c] * mask[c*R + r]
__global__ void transpose_mask(const float* __restrict__ in, const float* __restrict__ mask,
                               float* __restrict__ out, int R, int C) {
    __shared__ float tile[32][33];
    int cb = blockIdx.x * 32, rb = blockIdx.y * 32;
    int tx = threadIdx.x, ty = threadIdx.y;   // block (32,8)
    #pragma unroll
    for (int i = 0; i < 32; i += 8) {
        int r = rb + ty + i, c = cb + tx;
        if (r < R && c < C) tile[ty + i][tx] = in[(size_t)r * C + c];
    }
    __syncthreads();
    #pragma unroll
    for (int i = 0; i < 32; i += 8) {
        int c = cb + ty + i, r = rb + tx;
        if (c < C && r < R) {
            float v = tile[tx][ty + i];
            if (mask) v *= mask[(size_t)c * R + r];
            out[(size_t)c * R + r] = v;
        }
    }
}

__global__ void transpose_wout(const float* __restrict__ in, float* __restrict__ out) {
    int idx = blockIdx.x * blockDim.x + threadIdx.x;
    if (idx < NH * NO) {
        int j = idx / NO, o = idx % NO;
        out[idx] = in[o * NH + j];
    }
}

// A_norm: deterministic two-stage reduction
__global__ void anorm_stage1(const float* __restrict__ Wh11, const float* __restrict__ Wh22,
                             const float* __restrict__ mask, float* __restrict__ partial) {
    __shared__ float red[256];
    int tid = threadIdx.x;
    float s = 0.f;
    for (int idx = blockIdx.x * 256 + tid; idx < NH * NH; idx += 256 * 128) {
        int hh = idx / NH, j = idx % NH;
        s += fabsf(Wh11[idx] * mask[j * NH + hh]);
        s += fabsf(Wh22[idx] * mask[NH * NH + j * NH + hh]);
    }
    red[tid] = s;
    __syncthreads();
    for (int st = 128; st > 0; st >>= 1) {
        if (tid < st) red[tid] += red[tid + st];
        __syncthreads();
    }
    if (tid == 0) partial[blockIdx.x] = red[0];
}

__global__ void anorm_stage2(const float* __restrict__ partial, float* __restrict__ out) {
    __shared__ float red[128];
    int tid = threadIdx.x;
    red[tid] = partial[tid];
    __syncthreads();
    for (int st = 64; st > 0; st >>= 1) {
        if (tid < st) red[tid] += red[tid + st];
        __syncthreads();
    }
    if (tid == 0) out[0] = red[0];
}

// Deterministic, order-preserving block-wide stream compaction (16 waves).
__device__ __forceinline__ int block_compact(bool flag, int idx, int* list, int base,
                                             int* waveCnt, int tid) {
    unsigned long long m = __ballot(flag ? 1 : 0);
    int lane = tid & 63, w = tid >> 6;
    if (lane == 0) waveCnt[w] = __popcll(m);
    __syncthreads();
    int c[NWAVE];
    #pragma unroll
    for (int i = 0; i < NWAVE; ++i) c[i] = waveCnt[i];
    int off = base, tot = base;
    #pragma unroll
    for (int i = 0; i < NWAVE; ++i) {
        if (i < w) off += c[i];
        tot += c[i];
    }
    if (flag) list[off + __popcll(m & ((1ull << lane) - 1ull))] = idx;
    __syncthreads();
    return tot;
}

__device__ __forceinline__ void f4add(float4& a, const float4 b) {
    a.x += b.x; a.y += b.y; a.z += b.z; a.w += b.w;
}

__device__ __forceinline__ float4 ld4(const float* __restrict__ W, int j, int q) {
    return *reinterpret_cast<const float4*>(W + ((size_t)j << 9) + (q << 2));
}

// Gather a slice [kb,ke) of active rows of W: 8 indices -> 8 loads in flight -> 8 acc.
__device__ __forceinline__ float4 gather_slice(const int* __restrict__ list, int kb, int ke,
                                               const float* __restrict__ W, int q) {
    float4 a0{0,0,0,0}, a1{0,0,0,0}, a2{0,0,0,0}, a3{0,0,0,0},
           a4{0,0,0,0}, a5{0,0,0,0}, a6{0,0,0,0}, a7{0,0,0,0};
    int k = kb;
    for (; k + 7 < ke; k += 8) {
        int j[8];
        #pragma unroll
        for (int u = 0; u < 8; ++u) j[u] = list[k + u];
        float4 v0 = ld4(W, j[0], q), v1 = ld4(W, j[1], q),
               v2 = ld4(W, j[2], q), v3 = ld4(W, j[3], q),
               v4 = ld4(W, j[4], q), v5 = ld4(W, j[5], q),
               v6 = ld4(W, j[6], q), v7 = ld4(W, j[7], q);
        f4add(a0, v0); f4add(a1, v1); f4add(a2, v2); f4add(a3, v3);
        f4add(a4, v4); f4add(a5, v5); f4add(a6, v6); f4add(a7, v7);
    }
    for (; k < ke; ++k) f4add(a0, ld4(W, list[k], q));
    f4add(a0, a1); f4add(a2, a3); f4add(a4, a5); f4add(a6, a7);
    f4add(a0, a2); f4add(a4, a6); f4add(a0, a4);
    return a0;
}

// ---------------------------------------------------------------------------
// Main kernel: one block per batch sample, 1024 threads (16 waves), full T loop.
// __launch_bounds__(1024, 4): 4 waves/SIMD = exactly one resident block; lets the
// compiler use up to ~512 VGPRs -> no spills (round-3 regression was 64-VGPR spill).
__global__ __launch_bounds__(NT, 4) void snn_kernel(
    const float* __restrict__ input,
    const float* __restrict__ h1m0, const float* __restrict__ h2m0, const float* __restrict__ om0,
    const float* __restrict__ b_in, const float* __restrict__ b_h11,
    const float* __restrict__ b_h12, const float* __restrict__ b_h22,
    const float* __restrict__ b_o,
    const float* __restrict__ tau_adp_h1, const float* __restrict__ tau_adp_h2,
    const float* __restrict__ tau_m_h1, const float* __restrict__ tau_m_h2,
    const float* __restrict__ tau_m_o,
    const float* __restrict__ WinT, const float* __restrict__ Wh11T,
    const float* __restrict__ Wh12T, const float* __restrict__ Wh22T,
    const float* __restrict__ WoutT,
    float* __restrict__ out)
{
    __shared__ int actIn[NI];
    __shared__ int actS1[NH];
    __shared__ int actS2[NH];
    __shared__ int waveCnt[NWAVE];
    __shared__ float4 part4[8 * 128];     // 8 slices x 128 float4 = 16 KB
    __shared__ float part[320];

    const int tid = threadIdx.x;
    const int b = blockIdx.x;
    const int h = tid;            // neuron id (valid when tid < NH)
    const int s = tid >> 7;       // k-slice 0..7
    const int q = tid & 127;      // float4 column group
    const bool isN = tid < NH;
    const bool isI = tid < NI;

    float mem1 = 0.f, mem2 = 0.f, spk1 = 0.f, spk2 = 0.f, s1c = 0.f, s2c = 0.f;
    float al1 = 0.f, al2 = 0.f, ro1 = 0.f, ro2 = 0.f, bs1 = 0.f, bs2 = 0.f;
    if (isN) {
        mem1 = h1m0[b * NH + h];
        mem2 = h2m0[b * NH + h];
        al1 = expf(-1.f / tau_m_h1[h]);
        al2 = expf(-1.f / tau_m_h2[h]);
        ro1 = expf(-1.f / tau_adp_h1[h]);
        ro2 = expf(-1.f / tau_adp_h2[h]);
        bs1 = b_in[h] + b_h11[h];
        bs2 = b_h12[h] + b_h22[h];
    }

    float outm = 0.f, accO = 0.f, alo = 0.f, bo = 0.f;
    if (tid < NO) {
        outm = om0[b * NO + tid];
        alo = expf(-1.f / tau_m_o[tid]);
        bo = b_o[tid];
    }

    int nS1 = 0, nS2 = 0;
    const float* xbase = input + (size_t)b * TSTEPS * NI;

    // preload step-0 input (non-temporal: streamed once, keep weights in L2)
    float x0 = isI ? __builtin_nontemporal_load(xbase + tid) : 0.f;

    for (int t = 0; t < TSTEPS; ++t) {
        // ---- active input list (single compact over 700 indices, order preserved)
        bool f0 = x0 > 0.f;
        int nIn = block_compact(f0, tid, actIn, 0, waveCnt, tid);

        // prefetch next step's input; latency hides under the gather below
        if (t + 1 < TSTEPS && isI)
            x0 = __builtin_nontemporal_load(xbase + (size_t)(t + 1) * NI + tid);

        // ---- layer 1 gather: slice s of {active inputs -> WinT} + {active spk1 -> Wh11T}
        {
            float4 p = gather_slice(actIn, (nIn * s) >> 3, (nIn * (s + 1)) >> 3, WinT, q);
            float4 p2 = gather_slice(actS1, (nS1 * s) >> 3, (nS1 * (s + 1)) >> 3, Wh11T, q);
            f4add(p, p2);
            part4[(s << 7) + q] = p;
        }
        __syncthreads();
        const float* pf = (const float*)part4;
        float ns1 = 0.f;
        if (isN) {
            float i1 = (((pf[h] + pf[NH + h]) + (pf[2 * NH + h] + pf[3 * NH + h])) +
                        ((pf[4 * NH + h] + pf[5 * NH + h]) + (pf[6 * NH + h] + pf[7 * NH + h]))) + bs1;
            float b1 = ro1 * B_J0 + (1.f - ro1) * spk1;
            float B1 = B_J0 + BETA_ * b1;
            mem1 = mem1 * al1 + (1.f - al1) * i1 - B1 * spk1;
            ns1 = (mem1 - B1) > 0.f ? 1.f : 0.f;
            spk1 = ns1;
            s1c += ns1;
        }
        nS1 = block_compact(ns1 != 0.f, tid, actS1, 0, waveCnt, tid);

        // ---- layer 2 gather: {new spk1 -> Wh12T} + {old spk2 -> Wh22T}
        {
            float4 p = gather_slice(actS1, (nS1 * s) >> 3, (nS1 * (s + 1)) >> 3, Wh12T, q);
            float4 p2 = gather_slice(actS2, (nS2 * s) >> 3, (nS2 * (s + 1)) >> 3, Wh22T, q);
            f4add(p, p2);
            part4[(s << 7) + q] = p;
        }
        __syncthreads();
        float ns2 = 0.f;
        if (isN) {
            float i2 = (((pf[h] + pf[NH + h]) + (pf[2 * NH + h] + pf[3 * NH + h])) +
                        ((pf[4 * NH + h] + pf[5 * NH + h]) + (pf[6 * NH + h] + pf[7 * NH + h]))) + bs2;
            float b2 = ro2 * B_J0 + (1.f - ro2) * spk2;
            float B2 = B_J0 + BETA_ * b2;
            mem2 = mem2 * al2 + (1.f - al2) * i2 - B2 * spk2;
            ns2 = (mem2 - B2) > 0.f ? 1.f : 0.f;
            spk2 = ns2;
            s2c += ns2;
        }
        nS2 = block_compact(ns2 != 0.f, tid, actS2, 0, waveCnt, tid);

        // ---- readout: partials by 320 threads, finish inside wave 0
        if (tid < 320) {
            int o = tid % NO, r = tid / NO;
            float p = 0.f;
            for (int kk = r; kk < nS2; kk += 16) p += WoutT[actS2[kk] * NO + o];
            part[tid] = p;
        }
        __syncthreads();
        if (tid < 64) {
            float io = bo, v = -__builtin_huge_valf(), e = 0.f;
            if (tid < NO) {
                #pragma unroll
                for (int r = 0; r < 16; ++r) io += part[r * NO + tid];
                outm = outm * alo + (1.f - alo) * io;
                v = outm;
            }
            float mx = v;
            #pragma unroll
            for (int off = 16; off > 0; off >>= 1) mx = fmaxf(mx, __shfl_xor(mx, off, 32));
            if (tid < NO) e = expf(outm - mx);
            float ssum = e;
            #pragma unroll
            for (int off = 16; off > 0; off >>= 1) ssum += __shfl_xor(ssum, off, 32);
            if (tid < NO) accO += e / ssum;
        }
        // next loop's compact barrier orders part[] reuse
    }

    // ---- epilogue
    if (tid < NO) out[b * NO + tid] = accO;
    if (isN) {
        out[BATCH * NO + (size_t)b * NH + h] = s1c * (1.f / TSTEPS);
        out[BATCH * NO + BATCH * NH + (size_t)b * NH + h] = s2c * (1.f / TSTEPS);
    }
}

// ---------------------------------------------------------------------------
extern "C" void kernel_launch(void* const* d_in, const int* in_sizes, int n_in,
                              void* d_out, int out_size, void* d_ws, size_t ws_size,
                              hipStream_t stream) {
    const float* input      = (const float*)d_in[0];
    const float* mask       = (const float*)d_in[1];
    const float* h1m0       = (const float*)d_in[2];
    const float* h2m0       = (const float*)d_in[3];
    const float* om0        = (const float*)d_in[4];
    const float* W_in       = (const float*)d_in[5];
    const float* b_in       = (const float*)d_in[6];
    const float* W_h11      = (const float*)d_in[7];
    const float* b_h11      = (const float*)d_in[8];
    const float* W_h12      = (const float*)d_in[9];
    const float* b_h12      = (const float*)d_in[10];
    const float* W_h22      = (const float*)d_in[11];
    const float* b_h22      = (const float*)d_in[12];
    const float* W_out      = (const float*)d_in[13];
    const float* b_o        = (const float*)d_in[14];
    const float* tau_adp_h1 = (const float*)d_in[15];
    const float* tau_adp_h2 = (const float*)d_in[16];
    const float* tau_m_h1   = (const float*)d_in[17];
    const float* tau_m_h2   = (const float*)d_in[18];
    const float* tau_m_o    = (const float*)d_in[19];

    float* out = (float*)d_out;
    float* ws  = (float*)d_ws;

    float* WinT  = ws;                   // 700*512
    float* Wh11T = WinT + NI * NH;       // 512*512
    float* Wh12T = Wh11T + NH * NH;
    float* Wh22T = Wh12T + NH * NH;
    float* WoutT = Wh22T + NH * NH;      // 512*20
    float* apart = WoutT + NH * NO;      // 128 partials for anorm

    dim3 tb(32, 8);
    transpose_mask<<<dim3((NI + 31) / 32, (NH + 31) / 32), tb, 0, stream>>>(W_in, nullptr, WinT, NH, NI);
    transpose_mask<<<dim3(16, 16), tb, 0, stream>>>(W_h11, mask,            Wh11T, NH, NH);
    transpose_mask<<<dim3(16, 16), tb, 0, stream>>>(W_h12, nullptr,         Wh12T, NH, NH);
    transpose_mask<<<dim3(16, 16), tb, 0, stream>>>(W_h22, mask + NH * NH,  Wh22T, NH, NH);
    transpose_wout<<<(NH * NO + 255) / 256, 256, 0, stream>>>(W_out, WoutT);
    anorm_stage1<<<128, 256, 0, stream>>>(W_h11, W_h22, mask, apart);
    anorm_stage2<<<1, 128, 0, stream>>>(apart, out + BATCH * NO + 2 * BATCH * NH);

    snn_kernel<<<BATCH, NT, 0, stream>>>(input, h1m0, h2m0, om0,
        b_in, b_h11, b_h12, b_h22, b_o,
        tau_adp_h1, tau_adp_h2, tau_m_h1, tau_m_h2, tau_m_o,
        WinT, Wh11T, Wh12T, Wh22T, WoutT, out);
}

// Round 5
// 1464.215 us; speedup vs baseline: 2.1820x; 1.9647x over previous
//
#include <hip/hip_runtime.h>

// Problem constants (fixed by reference)
constexpr int BATCH = 256;
constexpr int TSTEPS = 250;
constexpr int NI = 700;
constexpr int NH = 512;
constexpr int NO = 20;

// float offsets of each transposed weight matrix inside the unified ws buffer
constexpr int OFF_WIN = 0;
constexpr int OFF_W11 = NI * NH;
constexpr int OFF_W12 = OFF_W11 + NH * NH;
constexpr int OFF_W22 = OFF_W12 + NH * NH;

#define B_J0  0.01f
#define BETA_ 1.8f

// ---------------------------------------------------------------------------
// Tiled transpose with optional mask fused:  out[c*R + r] = in[r*C + c] * mask[c*R + r]
__global__ void transpose_mask(const float* __restrict__ in, const float* __restrict__ mask,
                               float* __restrict__ out, int R, int C) {
    __shared__ float tile[32][33];
    int cb = blockIdx.x * 32, rb = blockIdx.y * 32;
    int tx = threadIdx.x, ty = threadIdx.y;   // block (32,8)
    #pragma unroll
    for (int i = 0; i < 32; i += 8) {
        int r = rb + ty + i, c = cb + tx;
        if (r < R && c < C) tile[ty + i][tx] = in[(size_t)r * C + c];
    }
    __syncthreads();
    #pragma unroll
    for (int i = 0; i < 32; i += 8) {
        int c = cb + ty + i, r = rb + tx;
        if (c < C && r < R) {
            float v = tile[tx][ty + i];
            if (mask) v *= mask[(size_t)c * R + r];
            out[(size_t)c * R + r] = v;
        }
    }
}

__global__ void transpose_wout(const float* __restrict__ in, float* __restrict__ out) {
    int idx = blockIdx.x * blockDim.x + threadIdx.x;
    if (idx < NH * NO) {
        int j = idx / NO, o = idx % NO;
        out[idx] = in[o * NH + j];
    }
}

// A_norm: deterministic two-stage reduction
__global__ void anorm_stage1(const float* __restrict__ Wh11, const float* __restrict__ Wh22,
                             const float* __restrict__ mask, float* __restrict__ partial) {
    __shared__ float red[256];
    int tid = threadIdx.x;
    float s = 0.f;
    for (int idx = blockIdx.x * 256 + tid; idx < NH * NH; idx += 256 * 128) {
        int hh = idx / NH, j = idx % NH;
        s += fabsf(Wh11[idx] * mask[j * NH + hh]);
        s += fabsf(Wh22[idx] * mask[NH * NH + j * NH + hh]);
    }
    red[tid] = s;
    __syncthreads();
    for (int st = 128; st > 0; st >>= 1) {
        if (tid < st) red[tid] += red[tid + st];
        __syncthreads();
    }
    if (tid == 0) partial[blockIdx.x] = red[0];
}

__global__ void anorm_stage2(const float* __restrict__ partial, float* __restrict__ out) {
    __shared__ float red[128];
    int tid = threadIdx.x;
    red[tid] = partial[tid];
    __syncthreads();
    for (int st = 64; st > 0; st >>= 1) {
        if (tid < st) red[tid] += red[tid + st];
        __syncthreads();
    }
    if (tid == 0) out[0] = red[0];
}

__device__ __forceinline__ void f4add(float4& a, const float4 b) {
    a.x += b.x; a.y += b.y; a.z += b.z; a.w += b.w;
}

// Gather rows [kb,ke) of the offset-list (entries are float offsets into ws),
// 8 named accumulators / 8 loads in flight. Threads of one slice read the same
// list entries (LDS broadcast) and consecutive 16B chunks of each 2KB row.
__device__ __forceinline__ float4 gather8(const int* __restrict__ list, int kb, int ke,
                                          const float* __restrict__ W, int q) {
    float4 a0{0,0,0,0}, a1{0,0,0,0}, a2{0,0,0,0}, a3{0,0,0,0},
           a4{0,0,0,0}, a5{0,0,0,0}, a6{0,0,0,0}, a7{0,0,0,0};
    int k = kb;
    const int q4 = q << 2;
    for (; k + 7 < ke; k += 8) {
        int o0 = list[k],     o1 = list[k + 1], o2 = list[k + 2], o3 = list[k + 3];
        int o4 = list[k + 4], o5 = list[k + 5], o6 = list[k + 6], o7 = list[k + 7];
        float4 v0 = *reinterpret_cast<const float4*>(W + o0 + q4);
        float4 v1 = *reinterpret_cast<const float4*>(W + o1 + q4);
        float4 v2 = *reinterpret_cast<const float4*>(W + o2 + q4);
        float4 v3 = *reinterpret_cast<const float4*>(W + o3 + q4);
        float4 v4 = *reinterpret_cast<const float4*>(W + o4 + q4);
        float4 v5 = *reinterpret_cast<const float4*>(W + o5 + q4);
        float4 v6 = *reinterpret_cast<const float4*>(W + o6 + q4);
        float4 v7 = *reinterpret_cast<const float4*>(W + o7 + q4);
        f4add(a0, v0); f4add(a1, v1); f4add(a2, v2); f4add(a3, v3);
        f4add(a4, v4); f4add(a5, v5); f4add(a6, v6); f4add(a7, v7);
    }
    for (; k < ke; ++k)
        f4add(a0, *reinterpret_cast<const float4*>(W + list[k] + q4));
    f4add(a0, a1); f4add(a2, a3); f4add(a4, a5); f4add(a6, a7);
    f4add(a0, a2); f4add(a4, a6); f4add(a0, a4);
    return a0;
}

// ---------------------------------------------------------------------------
// Main kernel: one block per batch sample, 512 threads (proven 80-VGPR config).
// Software-pipelined: iteration k computes spk1(step k) and spk2(step k-1) from
// ONE mega-gather phase; only 4 __syncthreads per step.
__global__ __launch_bounds__(NH, 2) void snn_kernel(
    const float* __restrict__ input,
    const float* __restrict__ h1m0, const float* __restrict__ h2m0, const float* __restrict__ om0,
    const float* __restrict__ b_in, const float* __restrict__ b_h11,
    const float* __restrict__ b_h12, const float* __restrict__ b_h22,
    const float* __restrict__ b_o,
    const float* __restrict__ tau_adp_h1, const float* __restrict__ tau_adp_h2,
    const float* __restrict__ tau_m_h1, const float* __restrict__ tau_m_h2,
    const float* __restrict__ tau_m_o,
    const float* __restrict__ ws, const float* __restrict__ WoutT,
    float* __restrict__ out)
{
    __shared__ int actA[NH + NI];        // [S1(k-1)->Wh11 | in(k)->Win]   (feeds i1)
    __shared__ int actB[2 * NH];         // [S1(k-1)->Wh12 | S2(k-2)->Wh22] (feeds i2)
    __shared__ int cnt1[8], cnt2[8], cntA[8], cntB[8];
    __shared__ float4 part4a[4 * 128];
    __shared__ float4 part4b[4 * 128];
    __shared__ float part[320];

    const int tid = threadIdx.x;
    const int b = blockIdx.x;
    const int h = tid;                    // neuron id (512 threads == NH)
    const int s = tid >> 7;               // slice 0..3
    const int q = tid & 127;              // float4 column group
    const int lane = tid & 63;
    const int w = tid >> 6;
    const unsigned long long ltmask = (1ull << lane) - 1ull;
    const bool hasTail = tid < (NI - NH); // handles input index 512+tid

    float mem1 = h1m0[b * NH + h];
    float mem2 = h2m0[b * NH + h];
    float spk1 = 0.f, spk2 = 0.f, s1c = 0.f, s2c = 0.f;
    const float al1 = expf(-1.f / tau_m_h1[h]);
    const float al2 = expf(-1.f / tau_m_h2[h]);
    const float ro1 = expf(-1.f / tau_adp_h1[h]);
    const float ro2 = expf(-1.f / tau_adp_h2[h]);
    const float bs1 = b_in[h] + b_h11[h];
    const float bs2 = b_h12[h] + b_h22[h];

    float outm = 0.f, accO = 0.f, alo = 0.f, bo = 0.f;
    if (tid < NO) {
        outm = om0[b * NO + tid];
        alo = expf(-1.f / tau_m_o[tid]);
        bo = b_o[tid];
    }

    const float* xbase = input + (size_t)b * TSTEPS * NI;

    // ---- prologue: compact inputs of step 0 into actA
    int lenA = 0, lenB = 0;
    {
        float xc0 = __builtin_nontemporal_load(xbase + tid);
        float xc1 = hasTail ? __builtin_nontemporal_load(xbase + NH + tid) : 0.f;
        unsigned long long mA = __ballot(xc0 > 0.f);
        unsigned long long mB = __ballot(hasTail && xc1 > 0.f);
        if (lane == 0) { cntA[w] = __popcll(mA); cntB[w] = __popcll(mB); }
        __syncthreads();
        int oA = 0, nA = 0, oB = 0, nB = 0;
        #pragma unroll
        for (int i = 0; i < 8; ++i) {
            int ca = cntA[i], cb = cntB[i];
            if (i < w) { oA += ca; oB += cb; }
            nA += ca; nB += cb;
        }
        if (xc0 > 0.f) actA[oA + __popcll(mA & ltmask)] = OFF_WIN + (tid << 9);
        if (hasTail && xc1 > 0.f) actA[nA + oB + __popcll(mB & ltmask)] = OFF_WIN + ((NH + tid) << 9);
        lenA = nA + nB;
        __syncthreads();
    }

    // ---- main pipeline: k = 0..TSTEPS (k<T: layer1 of step k; k>0: layer2+readout of step k-1)
    for (int k = 0; k <= TSTEPS; ++k) {
        const bool hasNext = (k + 1) < TSTEPS;
        // prefetch x_{k+1}; latency hides under the mega-gather
        float xn0 = 0.f, xn1 = 0.f;
        if (hasNext) {
            const float* xn = xbase + (size_t)(k + 1) * NI;
            xn0 = __builtin_nontemporal_load(xn + tid);
            xn1 = hasTail ? __builtin_nontemporal_load(xn + NH + tid) : 0.f;
        }

        // ---- P: mega gather (one long memory phase)
        if (k < TSTEPS) {
            float4 pa = gather8(actA, (lenA * s) >> 2, (lenA * (s + 1)) >> 2, ws, q);
            part4a[(s << 7) + q] = pa;
        }
        if (k > 0) {
            float4 pb = gather8(actB, (lenB * s) >> 2, (lenB * (s + 1)) >> 2, ws, q);
            part4b[(s << 7) + q] = pb;
        }
        __syncthreads();                                     // S1: partials ready

        // ---- U: neuron updates + all ballots
        const float* pfa = (const float*)part4a;
        const float* pfb = (const float*)part4b;
        float ns1 = 0.f, ns2 = 0.f;
        if (k < TSTEPS) {
            float i1 = ((pfa[h] + pfa[NH + h]) + (pfa[2 * NH + h] + pfa[3 * NH + h])) + bs1;
            float b1 = ro1 * B_J0 + (1.f - ro1) * spk1;
            float B1 = B_J0 + BETA_ * b1;
            mem1 = mem1 * al1 + (1.f - al1) * i1 - B1 * spk1;
            ns1 = (mem1 - B1) > 0.f ? 1.f : 0.f;
            spk1 = ns1; s1c += ns1;
        }
        if (k > 0) {
            float i2 = ((pfb[h] + pfb[NH + h]) + (pfb[2 * NH + h] + pfb[3 * NH + h])) + bs2;
            float b2 = ro2 * B_J0 + (1.f - ro2) * spk2;
            float B2 = B_J0 + BETA_ * b2;
            mem2 = mem2 * al2 + (1.f - al2) * i2 - B2 * spk2;
            ns2 = (mem2 - B2) > 0.f ? 1.f : 0.f;
            spk2 = ns2; s2c += ns2;
        }
        unsigned long long m1 = __ballot(ns1 != 0.f);
        unsigned long long m2 = __ballot(ns2 != 0.f);
        bool fA = hasNext && (xn0 > 0.f);
        bool fB = hasNext && hasTail && (xn1 > 0.f);
        unsigned long long mA = __ballot(fA);
        unsigned long long mB = __ballot(fB);
        if (lane == 0) {
            cnt1[w] = __popcll(m1); cnt2[w] = __popcll(m2);
            cntA[w] = __popcll(mA); cntB[w] = __popcll(mB);
        }
        __syncthreads();                                     // S2: counts ready

        // ---- W: rebuild lists (offsets precomputed into entries)
        int o1 = 0, n1 = 0, o2 = 0, n2 = 0, oA = 0, nA = 0, oB = 0, nB = 0;
        #pragma unroll
        for (int i = 0; i < 8; ++i) {
            int c1 = cnt1[i], c2 = cnt2[i], ca = cntA[i], cb = cntB[i];
            if (i < w) { o1 += c1; o2 += c2; oA += ca; oB += cb; }
            n1 += c1; n2 += c2; nA += ca; nB += cb;
        }
        if (ns1 != 0.f) {
            int p1 = o1 + __popcll(m1 & ltmask);
            actA[p1] = OFF_W11 + (h << 9);                   // feeds i1(k+1)
            actB[p1] = OFF_W12 + (h << 9);                   // feeds i2(k)
        }
        if (ns2 != 0.f)
            actB[n1 + o2 + __popcll(m2 & ltmask)] = OFF_W22 + (h << 9);   // feeds i2(k)
        if (fA) actA[n1 + oA + __popcll(mA & ltmask)] = OFF_WIN + (tid << 9);
        if (fB) actA[n1 + nA + oB + __popcll(mB & ltmask)] = OFF_WIN + ((NH + tid) << 9);
        lenA = n1 + nA + nB;
        lenB = n1 + n2;
        __syncthreads();                                     // S3: lists ready

        // ---- R: readout + softmax for step k-1 (uses spk2(k-1) = S2 segment of actB)
        if (k > 0) {
            if (tid < 320) {
                int o = tid % NO, r = tid / NO;
                float p = 0.f;
                for (int kk = r; kk < n2; kk += 16) {
                    int j = (actB[n1 + kk] - OFF_W22) >> 9;
                    p += WoutT[j * NO + o];
                }
                part[tid] = p;
            }
            __syncthreads();                                 // S4: partials ready
            if (tid < 64) {
                float io = bo, v = -__builtin_huge_valf(), e = 0.f;
                if (tid < NO) {
                    #pragma unroll
                    for (int r = 0; r < 16; ++r) io += part[r * NO + tid];
                    outm = outm * alo + (1.f - alo) * io;
                    v = outm;
                }
                float mx = v;
                #pragma unroll
                for (int off = 16; off > 0; off >>= 1) mx = fmaxf(mx, __shfl_xor(mx, off, 32));
                if (tid < NO) e = expf(outm - mx);
                float ssum = e;
                #pragma unroll
                for (int off = 16; off > 0; off >>= 1) ssum += __shfl_xor(ssum, off, 32);
                if (tid < NO) accO += e / ssum;
            }
        }
    }

    // ---- epilogue
    if (tid < NO) out[b * NO + tid] = accO;
    out[BATCH * NO + (size_t)b * NH + h] = s1c * (1.f / TSTEPS);
    out[BATCH * NO + BATCH * NH + (size_t)b * NH + h] = s2c * (1.f / TSTEPS);
}

// ---------------------------------------------------------------------------
extern "C" void kernel_launch(void* const* d_in, const int* in_sizes, int n_in,
                              void* d_out, int out_size, void* d_ws, size_t ws_size,
                              hipStream_t stream) {
    const float* input      = (const float*)d_in[0];
    const float* mask       = (const float*)d_in[1];
    const float* h1m0       = (const float*)d_in[2];
    const float* h2m0       = (const float*)d_in[3];
    const float* om0        = (const float*)d_in[4];
    const float* W_in       = (const float*)d_in[5];
    const float* b_in       = (const float*)d_in[6];
    const float* W_h11      = (const float*)d_in[7];
    const float* b_h11      = (const float*)d_in[8];
    const float* W_h12      = (const float*)d_in[9];
    const float* b_h12      = (const float*)d_in[10];
    const float* W_h22      = (const float*)d_in[11];
    const float* b_h22      = (const float*)d_in[12];
    const float* W_out      = (const float*)d_in[13];
    const float* b_o        = (const float*)d_in[14];
    const float* tau_adp_h1 = (const float*)d_in[15];
    const float* tau_adp_h2 = (const float*)d_in[16];
    const float* tau_m_h1   = (const float*)d_in[17];
    const float* tau_m_h2   = (const float*)d_in[18];
    const float* tau_m_o    = (const float*)d_in[19];

    float* out = (float*)d_out;
    float* ws  = (float*)d_ws;

    float* WinT  = ws + OFF_WIN;         // 700*512
    float* Wh11T = ws + OFF_W11;         // 512*512
    float* Wh12T = ws + OFF_W12;
    float* Wh22T = ws + OFF_W22;
    float* WoutT = Wh22T + NH * NH;      // 512*20
    float* apart = WoutT + NH * NO;      // 128 partials for anorm

    dim3 tb(32, 8);
    transpose_mask<<<dim3((NI + 31) / 32, (NH + 31) / 32), tb, 0, stream>>>(W_in, nullptr, WinT, NH, NI);
    transpose_mask<<<dim3(16, 16), tb, 0, stream>>>(W_h11, mask,            Wh11T, NH, NH);
    transpose_mask<<<dim3(16, 16), tb, 0, stream>>>(W_h12, nullptr,         Wh12T, NH, NH);
    transpose_mask<<<dim3(16, 16), tb, 0, stream>>>(W_h22, mask + NH * NH,  Wh22T, NH, NH);
    transpose_wout<<<(NH * NO + 255) / 256, 256, 0, stream>>>(W_out, WoutT);
    anorm_stage1<<<128, 256, 0, stream>>>(W_h11, W_h22, mask, apart);
    anorm_stage2<<<1, 128, 0, stream>>>(apart, out + BATCH * NO + 2 * BATCH * NH);

    snn_kernel<<<BATCH, NH, 0, stream>>>(input, h1m0, h2m0, om0,
        b_in, b_h11, b_h12, b_h22, b_o,
        tau_adp_h1, tau_adp_h2, tau_m_h1, tau_m_h2, tau_m_o,
        ws, WoutT, out);
}

// Round 6
// 1389.432 us; speedup vs baseline: 2.2994x; 1.0538x over previous
//
#include <hip/hip_runtime.h>

// Problem constants (fixed by reference)
constexpr int BATCH = 256;
constexpr int TSTEPS = 250;
constexpr int NI = 700;
constexpr int NH = 512;
constexpr int NO = 20;
constexpr int NT = 768;       // threads per block (12 waves)
constexpr int NWAVE = 12;
constexpr int NSLICE = 6;     // gather k-slices (128 threads each)

// float offsets of each transposed weight matrix inside the unified ws buffer
constexpr int OFF_WIN = 0;
constexpr int OFF_W11 = NI * NH;
constexpr int OFF_W12 = OFF_W11 + NH * NH;
constexpr int OFF_W22 = OFF_W12 + NH * NH;

#define B_J0  0.01f
#define BETA_ 1.8f

// ---------------------------------------------------------------------------
// Tiled transpose with optional mask fused:  out[c*R + r] = in[r*C + c] * mask[c*R + r]
__global__ void transpose_mask(const float* __restrict__ in, const float* __restrict__ mask,
                               float* __restrict__ out, int R, int C) {
    __shared__ float tile[32][33];
    int cb = blockIdx.x * 32, rb = blockIdx.y * 32;
    int tx = threadIdx.x, ty = threadIdx.y;   // block (32,8)
    #pragma unroll
    for (int i = 0; i < 32; i += 8) {
        int r = rb + ty + i, c = cb + tx;
        if (r < R && c < C) tile[ty + i][tx] = in[(size_t)r * C + c];
    }
    __syncthreads();
    #pragma unroll
    for (int i = 0; i < 32; i += 8) {
        int c = cb + ty + i, r = rb + tx;
        if (c < C && r < R) {
            float v = tile[tx][ty + i];
            if (mask) v *= mask[(size_t)c * R + r];
            out[(size_t)c * R + r] = v;
        }
    }
}

__global__ void transpose_wout(const float* __restrict__ in, float* __restrict__ out) {
    int idx = blockIdx.x * blockDim.x + threadIdx.x;
    if (idx < NH * NO) {
        int j = idx / NO, o = idx % NO;
        out[idx] = in[o * NH + j];
    }
}

// A_norm: deterministic two-stage reduction
__global__ void anorm_stage1(const float* __restrict__ Wh11, const float* __restrict__ Wh22,
                             const float* __restrict__ mask, float* __restrict__ partial) {
    __shared__ float red[256];
    int tid = threadIdx.x;
    float s = 0.f;
    for (int idx = blockIdx.x * 256 + tid; idx < NH * NH; idx += 256 * 128) {
        int hh = idx / NH, j = idx % NH;
        s += fabsf(Wh11[idx] * mask[j * NH + hh]);
        s += fabsf(Wh22[idx] * mask[NH * NH + j * NH + hh]);
    }
    red[tid] = s;
    __syncthreads();
    for (int st = 128; st > 0; st >>= 1) {
        if (tid < st) red[tid] += red[tid + st];
        __syncthreads();
    }
    if (tid == 0) partial[blockIdx.x] = red[0];
}

__global__ void anorm_stage2(const float* __restrict__ partial, float* __restrict__ out) {
    __shared__ float red[128];
    int tid = threadIdx.x;
    red[tid] = partial[tid];
    __syncthreads();
    for (int st = 64; st > 0; st >>= 1) {
        if (tid < st) red[tid] += red[tid + st];
        __syncthreads();
    }
    if (tid == 0) out[0] = red[0];
}

__device__ __forceinline__ void f4add(float4& a, const float4 b) {
    a.x += b.x; a.y += b.y; a.z += b.z; a.w += b.w;
}

// Gather rows [kb,ke) of the offset-list (entries are float offsets into ws),
// 8 named accumulators / 8 loads in flight (NO arrays: runtime-indexed arrays spill).
__device__ __forceinline__ float4 gather8(const int* __restrict__ list, int kb, int ke,
                                          const float* __restrict__ W, int q) {
    float4 a0{0,0,0,0}, a1{0,0,0,0}, a2{0,0,0,0}, a3{0,0,0,0},
           a4{0,0,0,0}, a5{0,0,0,0}, a6{0,0,0,0}, a7{0,0,0,0};
    int k = kb;
    const int q4 = q << 2;
    for (; k + 7 < ke; k += 8) {
        int o0 = list[k],     o1 = list[k + 1], o2 = list[k + 2], o3 = list[k + 3];
        int o4 = list[k + 4], o5 = list[k + 5], o6 = list[k + 6], o7 = list[k + 7];
        float4 v0 = *reinterpret_cast<const float4*>(W + o0 + q4);
        float4 v1 = *reinterpret_cast<const float4*>(W + o1 + q4);
        float4 v2 = *reinterpret_cast<const float4*>(W + o2 + q4);
        float4 v3 = *reinterpret_cast<const float4*>(W + o3 + q4);
        float4 v4 = *reinterpret_cast<const float4*>(W + o4 + q4);
        float4 v5 = *reinterpret_cast<const float4*>(W + o5 + q4);
        float4 v6 = *reinterpret_cast<const float4*>(W + o6 + q4);
        float4 v7 = *reinterpret_cast<const float4*>(W + o7 + q4);
        f4add(a0, v0); f4add(a1, v1); f4add(a2, v2); f4add(a3, v3);
        f4add(a4, v4); f4add(a5, v5); f4add(a6, v6); f4add(a7, v7);
    }
    for (; k < ke; ++k)
        f4add(a0, *reinterpret_cast<const float4*>(W + list[k] + q4));
    f4add(a0, a1); f4add(a2, a3); f4add(a4, a5); f4add(a6, a7);
    f4add(a0, a2); f4add(a4, a6); f4add(a0, a4);
    return a0;
}

// ---------------------------------------------------------------------------
// Main kernel: one block per batch sample, 768 threads (12 waves), full T loop.
// 3-stage software pipeline, 3 __syncthreads per step:
//   iter k:  P: gather i1(k) [actA] + i2(k-1) [actB] + readout partials for step k-2
//            U: spike updates spk1(k), spk2(k-1); softmax-finish step k-2; ballots
//            W: rebuild actA=[S1(k)|in(k+1)], actB=[S1(k)|S2(k-1)]
__global__ __launch_bounds__(NT, 3) void snn_kernel(
    const float* __restrict__ input,
    const float* __restrict__ h1m0, const float* __restrict__ h2m0, const float* __restrict__ om0,
    const float* __restrict__ b_in, const float* __restrict__ b_h11,
    const float* __restrict__ b_h12, const float* __restrict__ b_h22,
    const float* __restrict__ b_o,
    const float* __restrict__ tau_adp_h1, const float* __restrict__ tau_adp_h2,
    const float* __restrict__ tau_m_h1, const float* __restrict__ tau_m_h2,
    const float* __restrict__ tau_m_o,
    const float* __restrict__ ws, const float* __restrict__ WoutT,
    float* __restrict__ out)
{
    __shared__ int actA[NH + NI];        // [S1(k) | in(k+1)]   (feeds i1)
    __shared__ int actB[2 * NH];         // [S1(k) | S2(k-1)]   (feeds i2)
    __shared__ int cnt1[NWAVE], cnt2[NWAVE], cntI[NWAVE];
    __shared__ float4 part4a[NSLICE * 128];
    __shared__ float4 part4b[NSLICE * 128];
    __shared__ float part[320];

    const int tid = threadIdx.x;
    const int b = blockIdx.x;
    const int h = tid;                    // neuron id (valid when tid < NH)
    const int s = tid >> 7;               // slice 0..5
    const int q = tid & 127;              // float4 column group
    const int lane = tid & 63;
    const int w = tid >> 6;
    const unsigned long long ltmask = (1ull << lane) - 1ull;
    const bool isN = tid < NH;
    const bool isI = tid < NI;

    float mem1 = 0.f, mem2 = 0.f, spk1 = 0.f, spk2 = 0.f, s1c = 0.f, s2c = 0.f;
    float al1 = 0.f, al2 = 0.f, ro1 = 0.f, ro2 = 0.f, bs1 = 0.f, bs2 = 0.f;
    if (isN) {
        mem1 = h1m0[b * NH + h];
        mem2 = h2m0[b * NH + h];
        al1 = expf(-1.f / tau_m_h1[h]);
        al2 = expf(-1.f / tau_m_h2[h]);
        ro1 = expf(-1.f / tau_adp_h1[h]);
        ro2 = expf(-1.f / tau_adp_h2[h]);
        bs1 = b_in[h] + b_h11[h];
        bs2 = b_h12[h] + b_h22[h];
    }

    float outm = 0.f, accO = 0.f, alo = 0.f, bo = 0.f;
    if (tid < NO) {
        outm = om0[b * NO + tid];
        alo = expf(-1.f / tau_m_o[tid]);
        bo = b_o[tid];
    }

    const float* xbase = input + (size_t)b * TSTEPS * NI;

    // ---- prologue: compact inputs of step 0 into actA (lists: one compact, 768>=700)
    int lenA = 0, lenB = 0, prevN1 = 0, prevN2 = 0;
    {
        float xc = isI ? __builtin_nontemporal_load(xbase + tid) : 0.f;
        unsigned long long mI = __ballot(xc > 0.f);
        if (lane == 0) cntI[w] = __popcll(mI);
        __syncthreads();
        int oI = 0, nI = 0;
        #pragma unroll
        for (int i = 0; i < NWAVE; ++i) {
            int ci = cntI[i];
            if (i < w) oI += ci;
            nI += ci;
        }
        if (xc > 0.f) actA[oI + __popcll(mI & ltmask)] = OFF_WIN + (tid << 9);
        lenA = nI;
        __syncthreads();
    }

    // ---- main pipeline
    for (int k = 0; k <= TSTEPS + 1; ++k) {
        const bool hasNext = (k + 1) < TSTEPS;
        float xn = 0.f;
        if (hasNext && isI)
            xn = __builtin_nontemporal_load(xbase + (size_t)(k + 1) * NI + tid);

        // ---- P: mega gather + readout partials (step k-2)
        if (k < TSTEPS) {
            float4 pa = gather8(actA, (lenA * s) / NSLICE, (lenA * (s + 1)) / NSLICE, ws, q);
            part4a[(s << 7) + q] = pa;
        }
        if (k >= 1 && k <= TSTEPS) {
            float4 pb = gather8(actB, (lenB * s) / NSLICE, (lenB * (s + 1)) / NSLICE, ws, q);
            part4b[(s << 7) + q] = pb;
        }
        if (k >= 2 && tid < 320) {
            int o = tid % NO, r = tid / NO;
            float p = 0.f;
            for (int kk = r; kk < prevN2; kk += 16) {
                int j = (actB[prevN1 + kk] - OFF_W22) >> 9;
                p += WoutT[j * NO + o];
            }
            part[tid] = p;
        }
        __syncthreads();                                     // S1

        // ---- U: neuron updates, ballots, softmax-finish (step k-2)
        const float* pfa = (const float*)part4a;
        const float* pfb = (const float*)part4b;
        float ns1 = 0.f, ns2 = 0.f;
        if (k < TSTEPS && isN) {
            float i1 = (((pfa[h] + pfa[NH + h]) + (pfa[2 * NH + h] + pfa[3 * NH + h])) +
                        (pfa[4 * NH + h] + pfa[5 * NH + h])) + bs1;
            float b1 = ro1 * B_J0 + (1.f - ro1) * spk1;
            float B1 = B_J0 + BETA_ * b1;
            mem1 = mem1 * al1 + (1.f - al1) * i1 - B1 * spk1;
            ns1 = (mem1 - B1) > 0.f ? 1.f : 0.f;
            spk1 = ns1; s1c += ns1;
        }
        if (k >= 1 && k <= TSTEPS && isN) {
            float i2 = (((pfb[h] + pfb[NH + h]) + (pfb[2 * NH + h] + pfb[3 * NH + h])) +
                        (pfb[4 * NH + h] + pfb[5 * NH + h])) + bs2;
            float b2 = ro2 * B_J0 + (1.f - ro2) * spk2;
            float B2 = B_J0 + BETA_ * b2;
            mem2 = mem2 * al2 + (1.f - al2) * i2 - B2 * spk2;
            ns2 = (mem2 - B2) > 0.f ? 1.f : 0.f;
            spk2 = ns2; s2c += ns2;
        }
        unsigned long long m1 = __ballot(ns1 != 0.f);
        unsigned long long m2 = __ballot(ns2 != 0.f);
        bool fI = hasNext && isI && (xn > 0.f);
        unsigned long long mI = __ballot(fI);
        if (lane == 0) {
            cnt1[w] = __popcll(m1); cnt2[w] = __popcll(m2); cntI[w] = __popcll(mI);
        }
        if (k >= 2 && tid < 64) {
            float io = bo, v = -__builtin_huge_valf(), e = 0.f;
            if (tid < NO) {
                #pragma unroll
                for (int r = 0; r < 16; ++r) io += part[r * NO + tid];
                outm = outm * alo + (1.f - alo) * io;
                v = outm;
            }
            float mx = v;
            #pragma unroll
            for (int off = 16; off > 0; off >>= 1) mx = fmaxf(mx, __shfl_xor(mx, off, 32));
            if (tid < NO) e = expf(outm - mx);
            float ssum = e;
            #pragma unroll
            for (int off = 16; off > 0; off >>= 1) ssum += __shfl_xor(ssum, off, 32);
            if (tid < NO) accO += e / ssum;
        }
        __syncthreads();                                     // S2: counts ready

        // ---- W: rebuild lists (entries are precomputed float offsets)
        int o1 = 0, n1 = 0, o2 = 0, n2 = 0, oI = 0, nI = 0;
        #pragma unroll
        for (int i = 0; i < NWAVE; ++i) {
            int c1 = cnt1[i], c2 = cnt2[i], ci = cntI[i];
            if (i < w) { o1 += c1; o2 += c2; oI += ci; }
            n1 += c1; n2 += c2; nI += ci;
        }
        if (ns1 != 0.f) {
            int p1 = o1 + __popcll(m1 & ltmask);
            actA[p1] = OFF_W11 + (h << 9);                   // feeds i1(k+1)
            actB[p1] = OFF_W12 + (h << 9);                   // feeds i2(k)
        }
        if (ns2 != 0.f)
            actB[n1 + o2 + __popcll(m2 & ltmask)] = OFF_W22 + (h << 9);   // feeds i2(k)
        if (fI) actA[n1 + oI + __popcll(mI & ltmask)] = OFF_WIN + (tid << 9);
        lenA = n1 + nI;
        lenB = n1 + n2;
        prevN1 = n1; prevN2 = n2;                            // for readout at iter k+1
        __syncthreads();                                     // S3: lists ready
    }

    // ---- epilogue
    if (tid < NO) out[b * NO + tid] = accO;
    if (isN) {
        out[BATCH * NO + (size_t)b * NH + h] = s1c * (1.f / TSTEPS);
        out[BATCH * NO + BATCH * NH + (size_t)b * NH + h] = s2c * (1.f / TSTEPS);
    }
}

// ---------------------------------------------------------------------------
extern "C" void kernel_launch(void* const* d_in, const int* in_sizes, int n_in,
                              void* d_out, int out_size, void* d_ws, size_t ws_size,
                              hipStream_t stream) {
    const float* input      = (const float*)d_in[0];
    const float* mask       = (const float*)d_in[1];
    const float* h1m0       = (const float*)d_in[2];
    const float* h2m0       = (const float*)d_in[3];
    const float* om0        = (const float*)d_in[4];
    const float* W_in       = (const float*)d_in[5];
    const float* b_in       = (const float*)d_in[6];
    const float* W_h11      = (const float*)d_in[7];
    const float* b_h11      = (const float*)d_in[8];
    const float* W_h12      = (const float*)d_in[9];
    const float* b_h12      = (const float*)d_in[10];
    const float* W_h22      = (const float*)d_in[11];
    const float* b_h22      = (const float*)d_in[12];
    const float* W_out      = (const float*)d_in[13];
    const float* b_o        = (const float*)d_in[14];
    const float* tau_adp_h1 = (const float*)d_in[15];
    const float* tau_adp_h2 = (const float*)d_in[16];
    const float* tau_m_h1   = (const float*)d_in[17];
    const float* tau_m_h2   = (const float*)d_in[18];
    const float* tau_m_o    = (const float*)d_in[19];

    float* out = (float*)d_out;
    float* ws  = (float*)d_ws;

    float* WinT  = ws + OFF_WIN;         // 700*512
    float* Wh11T = ws + OFF_W11;         // 512*512
    float* Wh12T = ws + OFF_W12;
    float* Wh22T = ws + OFF_W22;
    float* WoutT = Wh22T + NH * NH;      // 512*20
    float* apart = WoutT + NH * NO;      // 128 partials for anorm

    dim3 tb(32, 8);
    transpose_mask<<<dim3((NI + 31) / 32, (NH + 31) / 32), tb, 0, stream>>>(W_in, nullptr, WinT, NH, NI);
    transpose_mask<<<dim3(16, 16), tb, 0, stream>>>(W_h11, mask,            Wh11T, NH, NH);
    transpose_mask<<<dim3(16, 16), tb, 0, stream>>>(W_h12, nullptr,         Wh12T, NH, NH);
    transpose_mask<<<dim3(16, 16), tb, 0, stream>>>(W_h22, mask + NH * NH,  Wh22T, NH, NH);
    transpose_wout<<<(NH * NO + 255) / 256, 256, 0, stream>>>(W_out, WoutT);
    anorm_stage1<<<128, 256, 0, stream>>>(W_h11, W_h22, mask, apart);
    anorm_stage2<<<1, 128, 0, stream>>>(apart, out + BATCH * NO + 2 * BATCH * NH);

    snn_kernel<<<BATCH, NT, 0, stream>>>(input, h1m0, h2m0, om0,
        b_in, b_h11, b_h12, b_h22, b_o,
        tau_adp_h1, tau_adp_h2, tau_m_h1, tau_m_h2, tau_m_o,
        ws, WoutT, out);
}